// Round 6
// baseline (333.007 us; speedup 1.0000x reference)
//
#include <hip/hip_runtime.h>
#include <hip/hip_bf16.h>

// KiloNeRF grouped tiny-MLP, expert-bucketed, point-per-half waves.
// Round-5 counters: VALUBusy 21%, occupancy 21% (VGPR=84 caps 16 waves/CU,
// drain leaves ~6.7), bank conflicts 3.0M from the half-offset W reads ->
// latency-bound. Round-6: one point per 32-lane HALF (both halves share the
// same W-row ds_reads -> broadcast, bank-optimal; no cross-half shfl combine;
// b128s per point halved), 512-thread blocks (8 waves/expert, 16 points per
// sweep = mean bucket size, __launch_bounds__(512,4) caps VGPR at 128 for
// 16 waves/CU). Single cross-wave barrier after weight staging.
//
// fp32 in / fp32 out. Expert-index arithmetic mirrors the reference's float32
// op order EXACTLY ((p+1.5f)/3.0f, *16, clip, trunc).

#define NPTS_BLK 512

// ---- workspace layout (ints) ----
#define WS_COUNTS 0
#define WS_OFFSETS 4096
#define WS_CURSOR 8192
#define WS_ORDER 12288

// ---- LDS weight slab (floats), transposed, padded strides ----
// W1T/WVT: 32 rows x 68 (real cols 63 / 59; pads zeroed). W2T/WFT: 32 x 36.
// Bank pattern for W-row b128 reads: lanes o=0..31 at o*68+i, both halves same
// address -> 32 addrs, 4 addrs per 4-bank span = 4 accesses/bank = optimal.
#define L_W1T   0
#define L_WVT   2176
#define L_W2T   4352
#define L_WFT   5504
#define L_WRGBT 6656     // 3 rows x 36
#define L_WSIG  6764
#define L_B1    6796
#define L_B2    6828
#define L_BF    6860
#define L_BV    6892
#define L_BSIG  6924
#define L_BRGB  6925
#define L_TOTAL 6928     // 27712 B

// per-POINT IO scratch (floats): 2 slices per wave (one per half)
#define IO_XP 0          // 64 (63 real, [63]=0)
#define IO_HV 64         // 64 (feat 0..31 | xd 32..58 | 59..63 = 0)
#define IO_H1 128        // 32
#define IO_H2 160        // 32
#define IO_PER_PT 192

__device__ __forceinline__ int expert_id(float px, float py, float pz) {
    float nx = (px - (-1.5f)) / 3.0f;
    float ny = (py - (-1.5f)) / 3.0f;
    float nz = (pz - (-1.5f)) / 3.0f;
    float sx = fminf(fmaxf(nx * 16.0f, 0.0f), 15.0f);
    float sy = fminf(fmaxf(ny * 16.0f, 0.0f), 15.0f);
    float sz = fminf(fmaxf(nz * 16.0f, 0.0f), 15.0f);
    return (int)sx * 256 + (int)sy * 16 + (int)sz;
}

// sum within each 32-lane half (xor offsets < 32 stay inside the half)
__device__ __forceinline__ float ws32(float v) {
#pragma unroll
    for (int off = 16; off >= 1; off >>= 1) v += __shfl_xor(v, off, 64);
    return v;
}

// posenc element j of 63: [c0,c1,c2, then per l: sin(2^l c0..c2), cos(2^l c0..c2)]
__device__ __forceinline__ float enc_elem(int j, float c0, float c1, float c2) {
    if (j < 3) return (j == 0) ? c0 : ((j == 1) ? c1 : c2);
    int k = j - 3, l = k / 6, r = k % 6;
    float c = ((r % 3) == 0) ? c0 : (((r % 3) == 1) ? c1 : c2);
    float a = ldexpf(c, l);
    return (r < 3) ? sinf(a) : cosf(a);
}

// full dot over NPAD padded inputs; W transposed row o, stride SW.
template <int NPAD, int SW>
__device__ __forceinline__ float matvec_full(const float* s_in, const float* wt, int o) {
    const float* wrow = wt + o * SW;
    float a0 = 0.f, a1 = 0.f, a2 = 0.f, a3 = 0.f;
#pragma unroll
    for (int i = 0; i < NPAD; i += 8) {
        float4 s4 = *(const float4*)(s_in + i);
        float4 w4 = *(const float4*)(wrow + i);
        a0 = fmaf(s4.x, w4.x, a0);
        a1 = fmaf(s4.y, w4.y, a1);
        a2 = fmaf(s4.z, w4.z, a2);
        a3 = fmaf(s4.w, w4.w, a3);
        float4 s5 = *(const float4*)(s_in + i + 4);
        float4 w5 = *(const float4*)(wrow + i + 4);
        a0 = fmaf(s5.x, w5.x, a0);
        a1 = fmaf(s5.y, w5.y, a1);
        a2 = fmaf(s5.z, w5.z, a2);
        a3 = fmaf(s5.w, w5.w, a3);
    }
    return (a0 + a2) + (a1 + a3);
}

// ---------------- pass A: histogram ----------------
__global__ __launch_bounds__(256) void hist_kernel(const float* __restrict__ pts,
                                                   int* __restrict__ counts, int n) {
    int i = blockIdx.x * 256 + threadIdx.x;
    if (i < n) {
        int e = expert_id(pts[3 * i + 0], pts[3 * i + 1], pts[3 * i + 2]);
        atomicAdd(&counts[e], 1);
    }
}

// ---------------- pass B: exclusive scan of 4096 counts (1 block) ----------
__global__ __launch_bounds__(256) void scan_kernel(const int* __restrict__ counts,
                                                   int* __restrict__ offsets,
                                                   int* __restrict__ cursor) {
    const int tid = threadIdx.x;
    const int lane = tid & 63, wave = tid >> 6;
    const int base = tid * 16;
    int c[16], loc[16], sum = 0;
#pragma unroll
    for (int j = 0; j < 16; ++j) c[j] = counts[base + j];
#pragma unroll
    for (int j = 0; j < 16; ++j) { loc[j] = sum; sum += c[j]; }
    int v = sum;
#pragma unroll
    for (int off = 1; off <= 32; off <<= 1) {
        int u = __shfl_up(v, off, 64);
        if (lane >= off) v += u;
    }
    __shared__ int wtot[4];
    if (lane == 63) wtot[wave] = v;
    __syncthreads();
    int wbase = 0;
    for (int w = 0; w < wave; ++w) wbase += wtot[w];
    const int excl = wbase + v - sum;
#pragma unroll
    for (int j = 0; j < 16; ++j) {
        int o = excl + loc[j];
        offsets[base + j] = o;
        cursor[base + j] = o;
    }
}

// ---------------- pass C: scatter point ids into buckets ----------------
__global__ __launch_bounds__(256) void scatter_kernel(const float* __restrict__ pts,
                                                      int* __restrict__ cursor,
                                                      int* __restrict__ order, int n) {
    int i = blockIdx.x * 256 + threadIdx.x;
    if (i < n) {
        int e = expert_id(pts[3 * i + 0], pts[3 * i + 1], pts[3 * i + 2]);
        int pos = atomicAdd(&cursor[e], 1);
        order[pos] = i;
    }
}

// ---------------- pass D: one block per expert, point-per-half ----------
__global__ __launch_bounds__(NPTS_BLK, 4) void expert_mlp_kernel(
    const float* __restrict__ pts, const float* __restrict__ viewdirs,
    const float* __restrict__ W1, const float* __restrict__ b1,
    const float* __restrict__ W2, const float* __restrict__ b2,
    const float* __restrict__ Wf, const float* __restrict__ bfc,
    const float* __restrict__ Wsig, const float* __restrict__ bsig,
    const float* __restrict__ Wv, const float* __restrict__ bv,
    const float* __restrict__ Wrgb, const float* __restrict__ brgb,
    const int* __restrict__ counts, const int* __restrict__ offsets,
    const int* __restrict__ order,
    float* __restrict__ out_rgb, float* __restrict__ out_sigma, int samples) {
    const int e = blockIdx.x;
    const int cnt = counts[e];
    if (cnt == 0) return;
    const int start = offsets[e];
    const int tid = threadIdx.x;
    const int wave = tid >> 6, lane = tid & 63;
    const int o = lane & 31, h = lane >> 5;   // h = which point of the pair

    __shared__ __align__(16) float lw[L_TOTAL];
    __shared__ __align__(16) float io[8 * 2 * IO_PER_PT];
    float* mine = io + (wave * 2 + h) * IO_PER_PT;   // this half's point slice

    // ---- stage weights transposed (coalesced global reads) ----
    for (int t = tid; t < 2016; t += NPTS_BLK) {
        int i = t >> 5, c = t & 31;
        lw[L_W1T + c * 68 + i] = W1[e * 2016 + t];
    }
    for (int t = tid; t < 1888; t += NPTS_BLK) {
        int i = t >> 5, c = t & 31;
        lw[L_WVT + c * 68 + i] = Wv[e * 1888 + t];
    }
    for (int t = tid; t < 1024; t += NPTS_BLK) {
        int i = t >> 5, c = t & 31;
        lw[L_W2T + c * 36 + i] = W2[e * 1024 + t];
        lw[L_WFT + c * 36 + i] = Wf[e * 1024 + t];
    }
    if (tid < 96) { int i = tid / 3, c = tid % 3; lw[L_WRGBT + c * 36 + i] = Wrgb[e * 96 + tid]; }
    else if (tid >= 128 && tid < 160) {
        int q = tid - 128;
        lw[L_WSIG + q] = Wsig[e * 32 + q];
        lw[L_B1 + q] = b1[e * 32 + q];
        lw[L_B2 + q] = b2[e * 32 + q];
        lw[L_BF + q] = bfc[e * 32 + q];
        lw[L_BV + q] = bv[e * 32 + q];
    } else if (tid >= 192 && tid < 224) {
        // zero pad col 63 of W1T rows
        lw[L_W1T + (tid - 192) * 68 + 63] = 0.f;
    } else if (tid >= 256 && tid < 416) {
        // zero pads 59..63 of WVT rows
        int z = tid - 256, c = z / 5, j = z % 5;
        lw[L_WVT + c * 68 + 59 + j] = 0.f;
    } else if (tid == 480) lw[L_BSIG] = bsig[e];
    else if (tid >= 481 && tid < 484) lw[L_BRGB + (tid - 481)] = brgb[e * 3 + (tid - 481)];

    // zero wave-private IO pads (never overwritten afterwards)
    if (o == 0) mine[IO_XP + 63] = 0.f;
    if (o < 5) mine[IO_HV + 59 + o] = 0.f;
    __syncthreads();   // the ONLY cross-wave barrier

    // ---- sweep: 8 waves x 2 halves = 16 points per pass ----
    for (int base = wave * 2; base < cnt; base += 16) {
        const int s = base + h;
        const bool valid = (s < cnt);
        const int pt = order[start + (valid ? s : base)];   // base < cnt always

        const float px = pts[3 * pt + 0];
        const float py = pts[3 * pt + 1];
        const float pz = pts[3 * pt + 2];
        const int ray = pt / samples;
        const float dxv = viewdirs[3 * ray + 0];
        const float dyv = viewdirs[3 * ray + 1];
        const float dzv = viewdirs[3 * ray + 2];

        // posenc(p): 32 lanes cover indices o and o+32
        mine[IO_XP + o] = enc_elem(o, px, py, pz);
        if (o < 31) mine[IO_XP + o + 32] = enc_elem(o + 32, px, py, pz);
        // posenc(d): indices 0..26
        if (o < 27) mine[IO_HV + 32 + o] = enc_elem(o, dxv, dyv, dzv);

        // layer 1: (63 -> 32) + relu
        float acc = matvec_full<64, 68>(mine + IO_XP, lw + L_W1T, o);
        float h1 = fmaxf(acc + lw[L_B1 + o], 0.f);
        mine[IO_H1 + o] = h1;

        // layer 2: (32 -> 32) + relu
        acc = matvec_full<32, 36>(mine + IO_H1, lw + L_W2T, o);
        float h2 = fmaxf(acc + lw[L_B2 + o], 0.f);
        mine[IO_H2 + o] = h2;

        // sigma head: per-half reduction
        {
            float pr = ws32(h2 * lw[L_WSIG + o]);
            if (o == 0 && valid) out_sigma[pt] = pr + lw[L_BSIG];
        }

        // feat: (32 -> 32), no relu -> hv[0:32]
        acc = matvec_full<32, 36>(mine + IO_H2, lw + L_WFT, o);
        mine[IO_HV + o] = acc + lw[L_BF + o];

        // view layer: (59 -> 32) + relu (stays in registers)
        acc = matvec_full<64, 68>(mine + IO_HV, lw + L_WVT, o);
        float hv = fmaxf(acc + lw[L_BV + o], 0.f);

        // rgb head: 3 per-half reductions
#pragma unroll
        for (int c = 0; c < 3; ++c) {
            float pr = ws32(hv * lw[L_WRGBT + c * 36 + o]);
            if (o == 0 && valid) out_rgb[3 * pt + c] = pr + lw[L_BRGB + c];
        }
    }
}

extern "C" void kernel_launch(void* const* d_in, const int* in_sizes, int n_in,
                              void* d_out, int out_size, void* d_ws, size_t ws_size,
                              hipStream_t stream) {
    const float* pts      = (const float*)d_in[0];
    const float* viewdirs = (const float*)d_in[1];
    const float* W1   = (const float*)d_in[2];
    const float* b1   = (const float*)d_in[3];
    const float* W2   = (const float*)d_in[4];
    const float* b2   = (const float*)d_in[5];
    const float* Wf   = (const float*)d_in[6];
    const float* bfc  = (const float*)d_in[7];
    const float* Wsig = (const float*)d_in[8];
    const float* bsig = (const float*)d_in[9];
    const float* Wv   = (const float*)d_in[10];
    const float* bv   = (const float*)d_in[11];
    const float* Wrgb = (const float*)d_in[12];
    const float* brgb = (const float*)d_in[13];

    const int n = in_sizes[0] / 3;          // 65536 points
    const int n_rays = in_sizes[1] / 3;     // 1024 rays
    const int samples = n / n_rays;         // 64 samples/ray

    float* out_rgb = (float*)d_out;
    float* out_sigma = out_rgb + (size_t)n * 3;

    int* ws = (int*)d_ws;
    int* counts = ws + WS_COUNTS;
    int* offsets = ws + WS_OFFSETS;
    int* cursor = ws + WS_CURSOR;
    int* order = ws + WS_ORDER;

    hipMemsetAsync(counts, 0, 4096 * sizeof(int), stream);
    hist_kernel<<<(n + 255) / 256, 256, 0, stream>>>(pts, counts, n);
    scan_kernel<<<1, 256, 0, stream>>>(counts, offsets, cursor);
    scatter_kernel<<<(n + 255) / 256, 256, 0, stream>>>(pts, cursor, order, n);
    expert_mlp_kernel<<<4096, NPTS_BLK, 0, stream>>>(
        pts, viewdirs, W1, b1, W2, b2, Wf, bfc, Wsig, bsig, Wv, bv, Wrgb, brgb,
        counts, offsets, order, out_rgb, out_sigma, samples);
}

// Round 8
// 316.983 us; speedup vs baseline: 1.0506x; 1.0506x over previous
//
#include <hip/hip_runtime.h>
#include <hip/hip_bf16.h>

// KiloNeRF grouped tiny-MLP — expert-bucketed, VGPR-resident f16 weights.
//
// Rounds 4-6 showed every LDS-staged variant is LDS-pipe bound (~96 b128/pt
// x 12cyc ~= 123us floor; measured 171-197us). Round-7/8: ONE WAVE PER EXPERT.
// Weights live in VGPRs as f16 pairs (row-split across the two 32-lane
// halves). Activations are broadcast with __shfl (one per ROW-PAIR via
// v_dot2_f32_f16, fp32 accumulate). No __shared__, no barriers; weight
// loads are one-time coalesced row reads.
//
// fp32 in / fp32 out. Expert bucketing (hist/scan/scatter) unchanged;
// expert-index arithmetic mirrors the reference's fp32 op order EXACTLY.

#define WS_COUNTS 0
#define WS_OFFSETS 4096
#define WS_CURSOR 8192
#define WS_ORDER 12288

typedef __fp16 half2v __attribute__((ext_vector_type(2)));

__device__ __forceinline__ int packh2(float a, float b) {
    half2v v = __builtin_amdgcn_cvt_pkrtz(a, b);   // lo=a, hi=b
    int r; __builtin_memcpy(&r, &v, 4); return r;
}

__device__ __forceinline__ float fdot2i(int w, int x, float acc) {
    half2v a, b; __builtin_memcpy(&a, &w, 4); __builtin_memcpy(&b, &x, 4);
#if __has_builtin(__builtin_amdgcn_fdot2)
    return __builtin_amdgcn_fdot2(a, b, acc, false);
#else
    return acc + (float)a.x * (float)b.x + (float)a.y * (float)b.y;
#endif
}

__device__ __forceinline__ int expert_id(float px, float py, float pz) {
    // EXACT fp32 op order of the reference
    float nx = (px - (-1.5f)) / 3.0f;
    float ny = (py - (-1.5f)) / 3.0f;
    float nz = (pz - (-1.5f)) / 3.0f;
    float sx = fminf(fmaxf(nx * 16.0f, 0.0f), 15.0f);
    float sy = fminf(fmaxf(ny * 16.0f, 0.0f), 15.0f);
    float sz = fminf(fmaxf(nz * 16.0f, 0.0f), 15.0f);
    return (int)sx * 256 + (int)sy * 16 + (int)sz;
}

// reduce within each 32-lane half; all lanes of the half get the sum
__device__ __forceinline__ float ws32(float v) {
#pragma unroll
    for (int off = 16; off >= 1; off >>= 1) v += __shfl_xor(v, off, 64);
    return v;
}

// posenc element precompute for index j: val = raw ? c[sel] : sin(c[sel]*freq + ph)
__device__ __forceinline__ void enc_pre(int j, float& freq, float& ph,
                                        int& sel, int& raw) {
    if (j < 3) { sel = j; freq = 1.f; ph = 0.f; raw = 1; return; }
    int k = j - 3, l = k / 6, rr = k % 6;
    sel = rr % 3;
    freq = (float)(1 << l);
    ph = (rr < 3) ? 0.f : 1.57079632679489662f;   // cos(x) = sin(x + pi/2)
    raw = 0;
}

__device__ __forceinline__ float enc_eval(float freq, float ph, int sel, int raw,
                                          float x, float y, float z) {
    float c = (sel == 0) ? x : ((sel == 1) ? y : z);
    float t = sinf(fmaf(c, freq, ph));
    return raw ? c : t;
}

// ---------------- pass A: histogram ----------------
__global__ __launch_bounds__(256) void hist_kernel(const float* __restrict__ pts,
                                                   int* __restrict__ counts, int n) {
    int i = blockIdx.x * 256 + threadIdx.x;
    if (i < n) {
        int e = expert_id(pts[3 * i + 0], pts[3 * i + 1], pts[3 * i + 2]);
        atomicAdd(&counts[e], 1);
    }
}

// ---------------- pass B: exclusive scan of 4096 counts (1 block) ----------
__global__ __launch_bounds__(256) void scan_kernel(const int* __restrict__ counts,
                                                   int* __restrict__ offsets,
                                                   int* __restrict__ cursor) {
    const int tid = threadIdx.x;
    const int lane = tid & 63, wave = tid >> 6;
    const int base = tid * 16;
    int c[16], loc[16], sum = 0;
#pragma unroll
    for (int j = 0; j < 16; ++j) c[j] = counts[base + j];
#pragma unroll
    for (int j = 0; j < 16; ++j) { loc[j] = sum; sum += c[j]; }
    int v = sum;
#pragma unroll
    for (int off = 1; off <= 32; off <<= 1) {
        int u = __shfl_up(v, off, 64);
        if (lane >= off) v += u;
    }
    __shared__ int wtot[4];
    if (lane == 63) wtot[wave] = v;
    __syncthreads();
    int wbase = 0;
    for (int w = 0; w < wave; ++w) wbase += wtot[w];
    const int excl = wbase + v - sum;
#pragma unroll
    for (int j = 0; j < 16; ++j) {
        int o = excl + loc[j];
        offsets[base + j] = o;
        cursor[base + j] = o;
    }
}

// ---------------- pass C: scatter point ids into buckets ----------------
__global__ __launch_bounds__(256) void scatter_kernel(const float* __restrict__ pts,
                                                      int* __restrict__ cursor,
                                                      int* __restrict__ order, int n) {
    int i = blockIdx.x * 256 + threadIdx.x;
    if (i < n) {
        int e = expert_id(pts[3 * i + 0], pts[3 * i + 1], pts[3 * i + 2]);
        int pos = atomicAdd(&cursor[e], 1);
        order[pos] = i;
    }
}

// ---------------- pass D: one WAVE per expert, register-resident weights ---
__global__ __launch_bounds__(256, 4) void expert_mlp_kernel(
    const float* __restrict__ pts, const float* __restrict__ viewdirs,
    const float* __restrict__ W1, const float* __restrict__ b1,
    const float* __restrict__ W2, const float* __restrict__ b2,
    const float* __restrict__ Wf, const float* __restrict__ bfc,
    const float* __restrict__ Wsig, const float* __restrict__ bsig,
    const float* __restrict__ Wv, const float* __restrict__ bv,
    const float* __restrict__ Wrgb, const float* __restrict__ brgb,
    const int* __restrict__ counts, const int* __restrict__ offsets,
    const int* __restrict__ order,
    float* __restrict__ out_rgb, float* __restrict__ out_sigma, int samples) {
    const int wave = threadIdx.x >> 6;
    const int lane = threadIdx.x & 63;
    const int e = blockIdx.x * 4 + wave;          // grid = 1024 x 256 -> e < 4096
    const int cnt = counts[e];
    if (cnt == 0) return;                          // no barriers in kernel: safe
    const int start = offsets[e];
    const int o = lane & 31, r = lane >> 5;

    // ---- load weights into VGPRs as f16 pairs ----
    // 64-wide layers (W1 63x32, Wv 59x32): pair j = rows (j, j+32), col o.
    // half r owns pairs j = 2t+r, t=0..15.  Coalesced row reads.
    const float* W1e = W1 + e * 2016;
    const float* Wve = Wv + e * 1888;
    const float* W2e = W2 + e * 1024;
    const float* Wfe = Wf + e * 1024;
    int w1p[16], wvp[16], w2p[8], wfp[8];
#pragma unroll
    for (int t = 0; t < 16; ++t) {
        int j = 2 * t + r;
        float lo = W1e[j * 32 + o];
        float hi = (j + 32 < 63) ? W1e[(j + 32) * 32 + o] : 0.f;
        w1p[t] = packh2(lo, hi);
    }
#pragma unroll
    for (int t = 0; t < 16; ++t) {
        int j = 2 * t + r;
        float lo = Wve[j * 32 + o];
        float hi = (j + 32 < 59) ? Wve[(j + 32) * 32 + o] : 0.f;
        wvp[t] = packh2(lo, hi);
    }
    // 32-wide layers: pair j = rows (j, j+16); half r owns j = 2t+r, t=0..7.
#pragma unroll
    for (int t = 0; t < 8; ++t) {
        int j = 2 * t + r;
        w2p[t] = packh2(W2e[j * 32 + o], W2e[(j + 16) * 32 + o]);
        wfp[t] = packh2(Wfe[j * 32 + o], Wfe[(j + 16) * 32 + o]);
    }
    const float b1r = b1[e * 32 + o];
    const float b2r = b2[e * 32 + o];
    const float bfr = bfc[e * 32 + o];
    const float bvr = bv[e * 32 + o];
    const float wsigr = Wsig[e * 32 + o];
    float wrgbr[3];
#pragma unroll
    for (int c = 0; c < 3; ++c) wrgbr[c] = Wrgb[e * 96 + o * 3 + c];
    const float bsig_v = bsig[e];
    const float brgb0 = brgb[e * 3 + 0], brgb1 = brgb[e * 3 + 1], brgb2 = brgb[e * 3 + 2];

    // ---- per-lane posenc precompute (constant across points) ----
    // slot A: xp[o];  slot B: xp[o+32] (o=31 -> zero);  slot D: xd[o] (o>=27 -> zero)
    float fA, pA, fB, pB, fD, pD; int sA, rA, sB, rB, sD, rD;
    enc_pre(o, fA, pA, sA, rA);
    enc_pre((o + 32 < 63) ? o + 32 : 0, fB, pB, sB, rB);
    const int zB = (o + 32 >= 63);
    enc_pre((o < 27) ? o : 0, fD, pD, sD, rD);
    const int zD = (o >= 27);

    // ---- stream this expert's points; prefetch next coords ----
    int pt = order[start];
    float px = pts[3 * pt + 0], py = pts[3 * pt + 1], pz = pts[3 * pt + 2];
    int ray = pt / samples;
    float dx = viewdirs[3 * ray + 0], dy = viewdirs[3 * ray + 1], dz = viewdirs[3 * ray + 2];

    for (int s = 0; s < cnt; ++s) {
        int ptn = pt; float pxn = px, pyn = py, pzn = pz, dxn = dx, dyn = dy, dzn = dz;
        if (s + 1 < cnt) {
            ptn = order[start + s + 1];
            pxn = pts[3 * ptn + 0]; pyn = pts[3 * ptn + 1]; pzn = pts[3 * ptn + 2];
            int rayn = ptn / samples;
            dxn = viewdirs[3 * rayn + 0]; dyn = viewdirs[3 * rayn + 1]; dzn = viewdirs[3 * rayn + 2];
        }

        // posenc -> packed pairs: lane j (j=o, both halves) holds (xp[j], xp[j+32])
        float xa = enc_eval(fA, pA, sA, rA, px, py, pz);
        float xb = zB ? 0.f : enc_eval(fB, pB, sB, rB, px, py, pz);
        int xpk = packh2(xa, xb);
        float xdv = zD ? 0.f : enc_eval(fD, pD, sD, rD, dx, dy, dz);

        // ---- layer 1: 63 -> 32, relu ----
        float a0 = 0.f, a1 = 0.f;
#pragma unroll
        for (int t = 0; t < 16; t += 2) {
            a0 = fdot2i(w1p[t],     __shfl(xpk, 2 * t + r, 64),       a0);
            a1 = fdot2i(w1p[t + 1], __shfl(xpk, 2 * (t + 1) + r, 64), a1);
        }
        float acc = a0 + a1;
        acc += __shfl_xor(acc, 32, 64);
        float h1 = fmaxf(acc + b1r, 0.f);

        // pack h1 pairs: lane with j=o&15 holds (h1[j], h1[j+16])
        float nb = __shfl_xor(h1, 16, 64);
        int h1k = (o & 16) ? packh2(nb, h1) : packh2(h1, nb);

        // ---- layer 2: 32 -> 32, relu ----
        a0 = 0.f; a1 = 0.f;
#pragma unroll
        for (int t = 0; t < 8; t += 2) {
            a0 = fdot2i(w2p[t],     __shfl(h1k, 2 * t + r, 64),       a0);
            a1 = fdot2i(w2p[t + 1], __shfl(h1k, 2 * (t + 1) + r, 64), a1);
        }
        acc = a0 + a1;
        acc += __shfl_xor(acc, 32, 64);
        float h2 = fmaxf(acc + b2r, 0.f);

        // ---- sigma head ----
        {
            float pr = ws32(h2 * wsigr);
            if (lane == 0) out_sigma[pt] = pr + bsig_v;
        }

        // pack h2 pairs
        nb = __shfl_xor(h2, 16, 64);
        int h2k = (o & 16) ? packh2(nb, h2) : packh2(h2, nb);

        // ---- feat: 32 -> 32, no relu ----
        a0 = 0.f; a1 = 0.f;
#pragma unroll
        for (int t = 0; t < 8; t += 2) {
            a0 = fdot2i(wfp[t],     __shfl(h2k, 2 * t + r, 64),       a0);
            a1 = fdot2i(wfp[t + 1], __shfl(h2k, 2 * (t + 1) + r, 64), a1);
        }
        acc = a0 + a1;
        acc += __shfl_xor(acc, 32, 64);
        float ft = acc + bfr;

        // pack view-layer input pairs: lane j=o holds (hv[j], hv[j+32]) = (feat[j], xd[j])
        int hvk = packh2(ft, xdv);

        // ---- view layer: 59 -> 32, relu ----
        a0 = 0.f; a1 = 0.f;
#pragma unroll
        for (int t = 0; t < 16; t += 2) {
            a0 = fdot2i(wvp[t],     __shfl(hvk, 2 * t + r, 64),       a0);
            a1 = fdot2i(wvp[t + 1], __shfl(hvk, 2 * (t + 1) + r, 64), a1);
        }
        acc = a0 + a1;
        acc += __shfl_xor(acc, 32, 64);
        float hv = fmaxf(acc + bvr, 0.f);

        // ---- rgb head ----
        float r0 = ws32(hv * wrgbr[0]);
        float r1 = ws32(hv * wrgbr[1]);
        float r2 = ws32(hv * wrgbr[2]);
        if (lane == 0) {
            out_rgb[3 * pt + 0] = r0 + brgb0;
            out_rgb[3 * pt + 1] = r1 + brgb1;
            out_rgb[3 * pt + 2] = r2 + brgb2;
        }

        pt = ptn; px = pxn; py = pyn; pz = pzn; dx = dxn; dy = dyn; dz = dzn;
    }
}

extern "C" void kernel_launch(void* const* d_in, const int* in_sizes, int n_in,
                              void* d_out, int out_size, void* d_ws, size_t ws_size,
                              hipStream_t stream) {
    const float* pts      = (const float*)d_in[0];
    const float* viewdirs = (const float*)d_in[1];
    const float* W1   = (const float*)d_in[2];
    const float* b1   = (const float*)d_in[3];
    const float* W2   = (const float*)d_in[4];
    const float* b2   = (const float*)d_in[5];
    const float* Wf   = (const float*)d_in[6];
    const float* bfc  = (const float*)d_in[7];
    const float* Wsig = (const float*)d_in[8];
    const float* bsig = (const float*)d_in[9];
    const float* Wv   = (const float*)d_in[10];
    const float* bv   = (const float*)d_in[11];
    const float* Wrgb = (const float*)d_in[12];
    const float* brgb = (const float*)d_in[13];

    const int n = in_sizes[0] / 3;          // 65536 points
    const int n_rays = in_sizes[1] / 3;     // 1024 rays
    const int samples = n / n_rays;         // 64 samples/ray

    float* out_rgb = (float*)d_out;
    float* out_sigma = out_rgb + (size_t)n * 3;

    int* ws = (int*)d_ws;
    int* counts = ws + WS_COUNTS;
    int* offsets = ws + WS_OFFSETS;
    int* cursor = ws + WS_CURSOR;
    int* order = ws + WS_ORDER;

    (void)hipMemsetAsync(counts, 0, 4096 * sizeof(int), stream);
    hist_kernel<<<(n + 255) / 256, 256, 0, stream>>>(pts, counts, n);
    scan_kernel<<<1, 256, 0, stream>>>(counts, offsets, cursor);
    scatter_kernel<<<(n + 255) / 256, 256, 0, stream>>>(pts, cursor, order, n);
    expert_mlp_kernel<<<1024, 256, 0, stream>>>(
        pts, viewdirs, W1, b1, W2, b2, Wf, bfc, Wsig, bsig, Wv, bv, Wrgb, brgb,
        counts, offsets, order, out_rgb, out_sigma, samples);
}